// Round 2
// baseline (5753.366 us; speedup 1.0000x reference)
//
#include <hip/hip_runtime.h>
#include <stdint.h>

// LSTM: B=128, T=512, I=256, H=512.
// 8 groups (16 batches) x 32 WGs (16 h-cols) = 256 WGs, 1/CU.
// Weights [W|U] resident in VGPRs as MFMA B-frags (K-partitioned over 4 waves).
// Per step: prefetch x-frag, flag-array barrier (parallel poll), load h (8B
// agent atomics), MFMA (M=16,N=64,K=768), conflict-free LDS reduce, gate math,
// publish h via agent stores + per-WG release flag.

#define B_ 128
#define T_ 512
#define I_ 256
#define H_ 512
#define NWG 32   // workgroups per group
#define NB 16    // batches per group

using short8 = __attribute__((ext_vector_type(8))) short;
using f32x4  = __attribute__((ext_vector_type(4))) float;

union V16 {
  uint32_t u[4];
  uint64_t q[2];
  short8 s;
};

__device__ __forceinline__ unsigned short bf16rne(float f) {
  uint32_t u = __builtin_bit_cast(uint32_t, f);
  u += 0x7fffu + ((u >> 16) & 1u);
  return (unsigned short)(u >> 16);
}

__device__ __forceinline__ short8 cvt8(float4 a, float4 b) {
  short8 r;
  r[0] = (short)bf16rne(a.x); r[1] = (short)bf16rne(a.y);
  r[2] = (short)bf16rne(a.z); r[3] = (short)bf16rne(a.w);
  r[4] = (short)bf16rne(b.x); r[5] = (short)bf16rne(b.y);
  r[6] = (short)bf16rne(b.z); r[7] = (short)bf16rne(b.w);
  return r;
}

__global__ __launch_bounds__(256, 1) void lstm_fused(
    const float* __restrict__ x,
    const float* __restrict__ Wi, const float* __restrict__ Ui, const float* __restrict__ bi,
    const float* __restrict__ Wf, const float* __restrict__ Uf, const float* __restrict__ bfv,
    const float* __restrict__ Wo, const float* __restrict__ Uo, const float* __restrict__ bo,
    const float* __restrict__ Wc, const float* __restrict__ Uc, const float* __restrict__ bc,
    float* __restrict__ out, uint32_t* __restrict__ ws)
{
  const int bid   = blockIdx.x;
  const int group = bid & 7;        // XCD-locality heuristic only (not correctness)
  const int wg    = bid >> 3;       // 0..31 within group
  const int tid   = threadIdx.x;
  const int lane  = tid & 63;
  const int wave  = tid >> 6;       // 0..3
  const int quad  = lane >> 4;      // 0..3
  const int row16 = lane & 15;      // A: batch row / B: output col
  const int bg0   = group * NB;
  const int col0  = wg * 16;

  // flags: group g at ws[g*128], slot wg at +wg*4 (16B spaced). 4 KB total.
  uint32_t* flags  = ws + group * 128;
  uint32_t* hbuf   = ws + 1024;                       // [2][128][256] dwords packed bf16
  uint64_t* hbuf64 = (uint64_t*)(ws + 1024);

  // partials: [m*16+n] rows (m=batch 0..15, n=col 0..15), 16 floats [w*4+g],
  // row stride 20 dwords => <=2-way bank aliasing on both b128 store and read.
  __shared__ float part[256 * 20];

  const float* Wg[4] = {Wi, Wf, Wo, Wc};
  const float* Ug[4] = {Ui, Uf, Uo, Uc};

  // ---- resident B (weight) fragments: wave covers K in [wave*192, wave*192+192) ----
  // B-frag 16x16x32: lane holds B[k=quad*8+j][n=lane&15]; weights are [n][k] row-major.
  short8 bfr[6][4];
  const int kbase = wave * 192;
  #pragma unroll
  for (int ki = 0; ki < 6; ++ki) {
    const int kk = kbase + ki * 32;
    const int k  = kk + quad * 8;
    #pragma unroll
    for (int g = 0; g < 4; ++g) {
      const float* src = (kk < 512)
        ? (Wg[g] + (size_t)(col0 + row16) * H_ + k)
        : (Ug[g] + (size_t)(col0 + row16) * I_ + (k - 512));
      float4 lo = *(const float4*)src;
      float4 hi = *(const float4*)(src + 4);
      bfr[ki][g] = cvt8(lo, hi);
    }
  }

  const int ub = tid >> 4;   // batch within group (update phase)
  const int uc = tid & 15;   // col within WG tile
  const float* bptr[4] = {bi, bfv, bo, bc};
  float bias[4];
  #pragma unroll
  for (int g = 0; g < 4; ++g) bias[g] = bptr[g][col0 + uc];

  float c_reg = 0.0f;

  for (int t = 0; t < T_; ++t) {
    // ---- prefetch x fragment (independent of the barrier) ----
    short8 afrag[6];
    #pragma unroll
    for (int ki = 0; ki < 6; ++ki) {
      const int kk = kbase + ki * 32;
      if (kk >= 512) {
        const int k = kk + quad * 8;
        const float* xp = x + ((size_t)(bg0 + row16) * T_ + t) * I_ + (k - 512);
        float4 lo = *(const float4*)xp;
        float4 hi = *(const float4*)(xp + 4);
        afrag[ki] = cvt8(lo, hi);
      }
    }

    // ---- barrier: wait until all 32 WGs of this group published step t ----
    if (t > 0) {
      if (wave == 0) {
        const uint32_t target = (uint32_t)t;
        bool done;
        do {
          uint32_t v = target;
          if (lane < 32)
            v = __hip_atomic_load(flags + lane * 4, __ATOMIC_ACQUIRE,
                                  __HIP_MEMORY_SCOPE_AGENT);
          done = __all((int)(v >= target));
        } while (!done);
      }
      __syncthreads();
    }

    // ---- load h fragments (8B agent-scope atomic loads) ----
    #pragma unroll
    for (int ki = 0; ki < 6; ++ki) {
      const int kk = kbase + ki * 32;
      if (kk < 512) {
        if (t > 0) {
          const uint32_t b64 = (uint32_t)(t & 1) * 16384u
                             + (uint32_t)(bg0 + row16) * 128u
                             + (uint32_t)(kk >> 2) + (uint32_t)(quad << 1);
          V16 v;
          v.q[0] = __hip_atomic_load(hbuf64 + b64,     __ATOMIC_RELAXED,
                                     __HIP_MEMORY_SCOPE_AGENT);
          v.q[1] = __hip_atomic_load(hbuf64 + b64 + 1, __ATOMIC_RELAXED,
                                     __HIP_MEMORY_SCOPE_AGENT);
          afrag[ki] = v.s;
        } else {
          V16 v; v.q[0] = 0; v.q[1] = 0;
          afrag[ki] = v.s;
        }
      }
    }

    // ---- MFMA: 6 K-iters x 4 gates ----
    f32x4 acc[4] = {{0.f,0.f,0.f,0.f},{0.f,0.f,0.f,0.f},
                    {0.f,0.f,0.f,0.f},{0.f,0.f,0.f,0.f}};
    #pragma unroll
    for (int ki = 0; ki < 6; ++ki) {
      #pragma unroll
      for (int g = 0; g < 4; ++g)
        acc[g] = __builtin_amdgcn_mfma_f32_16x16x32_bf16(afrag[ki], bfr[ki][g], acc[g], 0, 0, 0);
    }

    // ---- store partials transposed over gates: 4x b128, <=2-way banks ----
    // C/D layout: n = lane&15, m = quad*4 + reg.
    #pragma unroll
    for (int r = 0; r < 4; ++r) {
      f32x4 v;
      v[0] = acc[0][r]; v[1] = acc[1][r]; v[2] = acc[2][r]; v[3] = acc[3][r];
      *(f32x4*)&part[(((quad << 2) + r) * 16 + row16) * 20 + (wave << 2)] = v;
    }
    __syncthreads();

    // ---- reduce: thread tid handles (m=ub, n=uc); row = tid; 4x b128 reads ----
    const int rbase = tid * 20;
    f32x4 v0 = *(const f32x4*)&part[rbase];
    f32x4 v1 = *(const f32x4*)&part[rbase + 4];
    f32x4 v2 = *(const f32x4*)&part[rbase + 8];
    f32x4 v3 = *(const f32x4*)&part[rbase + 12];
    float pre[4];
    #pragma unroll
    for (int g = 0; g < 4; ++g)
      pre[g] = bias[g] + v0[g] + v1[g] + v2[g] + v3[g];

    const float ig = 1.0f / (1.0f + __expf(-pre[0]));
    const float fg = 1.0f / (1.0f + __expf(-pre[1]));
    const float og = 1.0f / (1.0f + __expf(-pre[2]));
    const float e2  = __expf(2.0f * pre[3]);
    const float ct  = (e2 - 1.0f) / (e2 + 1.0f);
    c_reg = fg * c_reg + ig * ct;
    const float e2c = __expf(2.0f * c_reg);
    const float tc  = (e2c - 1.0f) / (e2c + 1.0f);
    const float h   = og * tc;

    out[((size_t)(bg0 + ub) * T_ + t) * H_ + (col0 + uc)] = h;

    if (t == T_ - 1) {
      out[(size_t)B_ * T_ * H_ + (size_t)(bg0 + ub) * H_ + (col0 + uc)] = h;  // h_T
    } else {
      // publish h (packed bf16 pairs; even col holds low half)
      const float hpart = __shfl_xor(h, 1);
      if ((uc & 1) == 0) {
        const uint32_t v = (uint32_t)bf16rne(h) | ((uint32_t)bf16rne(hpart) << 16);
        const uint32_t idx = (uint32_t)((t + 1) & 1) * 32768u
                           + (uint32_t)(bg0 + ub) * 256u
                           + (uint32_t)((col0 + uc) >> 1);
        __hip_atomic_store(hbuf + idx, v, __ATOMIC_RELAXED, __HIP_MEMORY_SCOPE_AGENT);
      }
      __syncthreads();   // all waves' h stores drained (vmcnt0) before the flag
      if (tid == 0)
        __hip_atomic_store(flags + wg * 4, (uint32_t)(t + 1), __ATOMIC_RELEASE,
                           __HIP_MEMORY_SCOPE_AGENT);
    }
  }

  // c_T
  out[(size_t)B_ * T_ * H_ + (size_t)B_ * H_ + (size_t)(bg0 + ub) * H_ + (col0 + uc)] = c_reg;
}

extern "C" void kernel_launch(void* const* d_in, const int* in_sizes, int n_in,
                              void* d_out, int out_size, void* d_ws, size_t ws_size,
                              hipStream_t stream) {
  // ws layout: [0,4KB): per-WG flag slots (zeroed each launch)
  //            [4KB, 4KB+256KB): double-buffered packed-bf16 h exchange
  hipMemsetAsync(d_ws, 0, 4096, stream);
  dim3 grid(256), block(256);
  lstm_fused<<<grid, block, 0, stream>>>(
      (const float*)d_in[0],
      (const float*)d_in[1], (const float*)d_in[2], (const float*)d_in[3],
      (const float*)d_in[4], (const float*)d_in[5], (const float*)d_in[6],
      (const float*)d_in[7], (const float*)d_in[8], (const float*)d_in[9],
      (const float*)d_in[10], (const float*)d_in[11], (const float*)d_in[12],
      (float*)d_out, (uint32_t*)d_ws);
}

// Round 3
// 3523.831 us; speedup vs baseline: 1.6327x; 1.6327x over previous
//
#include <hip/hip_runtime.h>
#include <stdint.h>

// LSTM: B=128, T=512, I=256, H=512.
// 8 groups (16 batches) x 32 WGs (16 h-cols) = 256 WGs, 1/CU.
// Weights [W|U] resident in VGPRs as MFMA B-frags (K-partitioned over 4 waves).
// Per step: prefetch x-frag, RELAXED flag-array poll (sc1, no cache maintenance),
// load h (8B relaxed sc1 loads), MFMA (M=16,N=64,K=768), conflict-free LDS
// reduce, gate math, publish h (relaxed sc1) + syncthreads (vmcnt0 drain) +
// relaxed flag store. Release/acquire orderings deliberately avoided: at agent
// scope they emit buffer_wbl2/buffer_inv (whole-L2 maintenance) per op, which
// was the R0/R1 bottleneck.

#define B_ 128
#define T_ 512
#define I_ 256
#define H_ 512
#define NWG 32   // workgroups per group
#define NB 16    // batches per group

using short8 = __attribute__((ext_vector_type(8))) short;
using f32x4  = __attribute__((ext_vector_type(4))) float;

union V16 {
  uint32_t u[4];
  uint64_t q[2];
  short8 s;
};

__device__ __forceinline__ unsigned short bf16rne(float f) {
  uint32_t u = __builtin_bit_cast(uint32_t, f);
  u += 0x7fffu + ((u >> 16) & 1u);
  return (unsigned short)(u >> 16);
}

__device__ __forceinline__ short8 cvt8(float4 a, float4 b) {
  short8 r;
  r[0] = (short)bf16rne(a.x); r[1] = (short)bf16rne(a.y);
  r[2] = (short)bf16rne(a.z); r[3] = (short)bf16rne(a.w);
  r[4] = (short)bf16rne(b.x); r[5] = (short)bf16rne(b.y);
  r[6] = (short)bf16rne(b.z); r[7] = (short)bf16rne(b.w);
  return r;
}

__global__ __launch_bounds__(256, 1) void lstm_fused(
    const float* __restrict__ x,
    const float* __restrict__ Wi, const float* __restrict__ Ui, const float* __restrict__ bi,
    const float* __restrict__ Wf, const float* __restrict__ Uf, const float* __restrict__ bfv,
    const float* __restrict__ Wo, const float* __restrict__ Uo, const float* __restrict__ bo,
    const float* __restrict__ Wc, const float* __restrict__ Uc, const float* __restrict__ bc,
    float* __restrict__ out, uint32_t* __restrict__ ws)
{
  const int bid   = blockIdx.x;
  const int group = bid & 7;        // XCD-locality heuristic only (not correctness)
  const int wg    = bid >> 3;       // 0..31 within group
  const int tid   = threadIdx.x;
  const int lane  = tid & 63;
  const int wave  = tid >> 6;       // 0..3
  const int quad  = lane >> 4;      // 0..3
  const int row16 = lane & 15;      // A: batch row / B: output col
  const int bg0   = group * NB;
  const int col0  = wg * 16;

  // flags: group g at ws[g*512], slot wg at +wg*16 (64B = own cacheline). 16 KB.
  uint32_t* flags  = ws + group * 512;
  uint32_t* hbuf   = ws + 4096;                       // [2][128][256] dwords packed bf16
  uint64_t* hbuf64 = (uint64_t*)(ws + 4096);

  // partials: [m*16+n] rows, 16 floats [w*4+g], row stride 20 dwords
  // => <=2-way bank aliasing (free) on both b128 store and read.
  __shared__ float part[256 * 20];

  const float* Wg[4] = {Wi, Wf, Wo, Wc};
  const float* Ug[4] = {Ui, Uf, Uo, Uc};

  // ---- resident B (weight) fragments: wave covers K in [wave*192, wave*192+192) ----
  // B-frag 16x16x32: lane holds B[k=quad*8+j][n=lane&15]; weights are [n][k] row-major.
  short8 bfr[6][4];
  const int kbase = wave * 192;
  #pragma unroll
  for (int ki = 0; ki < 6; ++ki) {
    const int kk = kbase + ki * 32;
    const int k  = kk + quad * 8;
    #pragma unroll
    for (int g = 0; g < 4; ++g) {
      const float* src = (kk < 512)
        ? (Wg[g] + (size_t)(col0 + row16) * H_ + k)
        : (Ug[g] + (size_t)(col0 + row16) * I_ + (k - 512));
      float4 lo = *(const float4*)src;
      float4 hi = *(const float4*)(src + 4);
      bfr[ki][g] = cvt8(lo, hi);
    }
  }

  const int ub = tid >> 4;   // batch within group (update phase)
  const int uc = tid & 15;   // col within WG tile
  const float* bptr[4] = {bi, bfv, bo, bc};
  float bias[4];
  #pragma unroll
  for (int g = 0; g < 4; ++g) bias[g] = bptr[g][col0 + uc];

  float c_reg = 0.0f;

  for (int t = 0; t < T_; ++t) {
    // ---- prefetch x fragment (independent of the barrier) ----
    short8 afrag[6];
    #pragma unroll
    for (int ki = 0; ki < 6; ++ki) {
      const int kk = kbase + ki * 32;
      if (kk >= 512) {
        const int k = kk + quad * 8;
        const float* xp = x + ((size_t)(bg0 + row16) * T_ + t) * I_ + (k - 512);
        float4 lo = *(const float4*)xp;
        float4 hi = *(const float4*)(xp + 4);
        afrag[ki] = cvt8(lo, hi);
      }
    }

    // ---- barrier: wait until all 32 WGs of this group published step t ----
    // RELAXED poll: sc1 load straight from L3 (coherence point); no buffer_inv.
    if (t > 0) {
      if (wave == 0) {
        const uint32_t target = (uint32_t)t;
        bool done;
        do {
          uint32_t v = target;
          if (lane < 32)
            v = __hip_atomic_load(flags + lane * 16, __ATOMIC_RELAXED,
                                  __HIP_MEMORY_SCOPE_AGENT);
          done = __all((int)(v >= target));
        } while (!done);
      }
      __syncthreads();
    }

    // ---- load h fragments (8B relaxed sc1 loads from L3) ----
    #pragma unroll
    for (int ki = 0; ki < 6; ++ki) {
      const int kk = kbase + ki * 32;
      if (kk < 512) {
        if (t > 0) {
          const uint32_t b64 = (uint32_t)(t & 1) * 16384u
                             + (uint32_t)(bg0 + row16) * 128u
                             + (uint32_t)(kk >> 2) + (uint32_t)(quad << 1);
          V16 v;
          v.q[0] = __hip_atomic_load(hbuf64 + b64,     __ATOMIC_RELAXED,
                                     __HIP_MEMORY_SCOPE_AGENT);
          v.q[1] = __hip_atomic_load(hbuf64 + b64 + 1, __ATOMIC_RELAXED,
                                     __HIP_MEMORY_SCOPE_AGENT);
          afrag[ki] = v.s;
        } else {
          V16 v; v.q[0] = 0; v.q[1] = 0;
          afrag[ki] = v.s;
        }
      }
    }

    // ---- MFMA: 6 K-iters x 4 gates ----
    f32x4 acc[4] = {{0.f,0.f,0.f,0.f},{0.f,0.f,0.f,0.f},
                    {0.f,0.f,0.f,0.f},{0.f,0.f,0.f,0.f}};
    #pragma unroll
    for (int ki = 0; ki < 6; ++ki) {
      #pragma unroll
      for (int g = 0; g < 4; ++g)
        acc[g] = __builtin_amdgcn_mfma_f32_16x16x32_bf16(afrag[ki], bfr[ki][g], acc[g], 0, 0, 0);
    }

    // ---- store partials transposed over gates: 4x b128, <=2-way banks ----
    // C/D layout: n = lane&15, m = quad*4 + reg.
    #pragma unroll
    for (int r = 0; r < 4; ++r) {
      f32x4 v;
      v[0] = acc[0][r]; v[1] = acc[1][r]; v[2] = acc[2][r]; v[3] = acc[3][r];
      *(f32x4*)&part[(((quad << 2) + r) * 16 + row16) * 20 + (wave << 2)] = v;
    }
    __syncthreads();

    // ---- reduce: thread tid handles (m=ub, n=uc); row = tid; 4x b128 reads ----
    const int rbase = tid * 20;
    f32x4 v0 = *(const f32x4*)&part[rbase];
    f32x4 v1 = *(const f32x4*)&part[rbase + 4];
    f32x4 v2 = *(const f32x4*)&part[rbase + 8];
    f32x4 v3 = *(const f32x4*)&part[rbase + 12];
    float pre[4];
    #pragma unroll
    for (int g = 0; g < 4; ++g)
      pre[g] = bias[g] + v0[g] + v1[g] + v2[g] + v3[g];

    const float ig = 1.0f / (1.0f + __expf(-pre[0]));
    const float fg = 1.0f / (1.0f + __expf(-pre[1]));
    const float og = 1.0f / (1.0f + __expf(-pre[2]));
    const float e2  = __expf(2.0f * pre[3]);
    const float ct  = (e2 - 1.0f) / (e2 + 1.0f);
    c_reg = fg * c_reg + ig * ct;
    const float e2c = __expf(2.0f * c_reg);
    const float tc  = (e2c - 1.0f) / (e2c + 1.0f);
    const float h   = og * tc;

    if (t < T_ - 1) {
      // publish h FIRST (packed bf16 pairs; even col holds low half) so the
      // flag release isn't waiting on the out[] store ack.
      const float hpart = __shfl_xor(h, 1);
      if ((uc & 1) == 0) {
        const uint32_t v = (uint32_t)bf16rne(h) | ((uint32_t)bf16rne(hpart) << 16);
        const uint32_t idx = (uint32_t)((t + 1) & 1) * 32768u
                           + (uint32_t)(bg0 + ub) * 256u
                           + (uint32_t)((col0 + uc) >> 1);
        __hip_atomic_store(hbuf + idx, v, __ATOMIC_RELAXED, __HIP_MEMORY_SCOPE_AGENT);
      }
      // compiler emits s_waitcnt vmcnt(0) before s_barrier => all waves' sc1
      // h-stores are acked at L3 before the flag store issues (release pattern
      // without buffer_wbl2, valid because prior writes are themselves sc1).
      __syncthreads();
      if (tid == 0)
        __hip_atomic_store(flags + wg * 16, (uint32_t)(t + 1), __ATOMIC_RELAXED,
                           __HIP_MEMORY_SCOPE_AGENT);
    } else {
      out[(size_t)B_ * T_ * H_ + (size_t)(bg0 + ub) * H_ + (col0 + uc)] = h;  // h_T
    }

    out[((size_t)(bg0 + ub) * T_ + t) * H_ + (col0 + uc)] = h;
  }

  // c_T
  out[(size_t)B_ * T_ * H_ + (size_t)B_ * H_ + (size_t)(bg0 + ub) * H_ + (col0 + uc)] = c_reg;
}

extern "C" void kernel_launch(void* const* d_in, const int* in_sizes, int n_in,
                              void* d_out, int out_size, void* d_ws, size_t ws_size,
                              hipStream_t stream) {
  // ws layout: [0,16KB): per-WG flag slots, 64B-spaced (zeroed each launch)
  //            [16KB, 16KB+256KB): double-buffered packed-bf16 h exchange
  hipMemsetAsync(d_ws, 0, 16384, stream);
  dim3 grid(256), block(256);
  lstm_fused<<<grid, block, 0, stream>>>(
      (const float*)d_in[0],
      (const float*)d_in[1], (const float*)d_in[2], (const float*)d_in[3],
      (const float*)d_in[4], (const float*)d_in[5], (const float*)d_in[6],
      (const float*)d_in[7], (const float*)d_in[8], (const float*)d_in[9],
      (const float*)d_in[10], (const float*)d_in[11], (const float*)d_in[12],
      (float*)d_out, (uint32_t*)d_ws);
}